// Round 1
// baseline (519.211 us; speedup 1.0000x reference)
//
#include <hip/hip_runtime.h>

#define LB __launch_bounds__(256)

// ---------------------------------------------------------------------------
// Weight pre-transpose:
//  wc [64][256]        -> wcT [256][64]           (c-major, 16-cons. outputs)
//  we [36][64][9]      -> weT [pq=4][i=64][kt=9][kk=9]  (kk contiguous)
// ---------------------------------------------------------------------------
__global__ LB void prep_weights(
    const float* __restrict__ wcA, const float* __restrict__ wcB,
    const float* __restrict__ wcC, const float* __restrict__ wcD,
    const float* __restrict__ weA, const float* __restrict__ weB,
    const float* __restrict__ weC, const float* __restrict__ weD,
    float* __restrict__ wcT, float* __restrict__ weT)
{
    int seg = blockIdx.y;
    int t = blockIdx.x * 256 + threadIdx.x;
    if (seg < 4) {
        if (t >= 64 * 256) return;
        const float* w = (seg == 0) ? wcA : (seg == 1) ? wcB : (seg == 2) ? wcC : wcD;
        int c = t & 255, o = t >> 8;          // t = o*256 + c  (coalesced read)
        wcT[seg * 16384 + c * 64 + o] = w[t];
    } else {
        if (t >= 36 * 64 * 9) return;
        const float* w = (seg == 4) ? weA : (seg == 5) ? weB : (seg == 6) ? weC : weD;
        int kt = t % 9;
        int r = t / 9;
        int i = r & 63;
        int o = r >> 6;                        // t = (o*64+i)*9+kt (coalesced read)
        int kk = o >> 2, pq = o & 3;
        weT[(seg - 4) * 20736 + ((pq * 64 + i) * 9 + kt) * 9 + kk] = w[t];
    }
}

// ---------------------------------------------------------------------------
// K1: 1x1 conv 256 -> 64.  block = 4 o-groups x 64 pixels.
// Weights read as wave-uniform scalar loads (wcT[c][64]).
// ---------------------------------------------------------------------------
__global__ LB void compress_k(const float* __restrict__ x, const float* __restrict__ wcT,
                              const float* __restrict__ bc, float* __restrict__ comp, int lgW)
{
    int lane = threadIdx.x & 63;
    int og = __builtin_amdgcn_readfirstlane(threadIdx.x >> 6);
    int lgHW = 2 * lgW;
    int HW = 1 << lgHW;
    int pix = blockIdx.x * 64 + lane;
    int b = pix >> lgHW;
    int hw = pix & (HW - 1);
    const float* xp = x + ((size_t)b << lgHW) * 256 + hw;
    float acc[16];
    const float* bp = bc + og * 16;
    #pragma unroll
    for (int j = 0; j < 16; j++) acc[j] = bp[j];
    const float* wr = wcT + og * 16;
    #pragma unroll 4
    for (int c = 0; c < 256; c++) {
        float xv = xp[(size_t)c << lgHW];
        #pragma unroll
        for (int j = 0; j < 16; j++) acc[j] += wr[c * 64 + j] * xv;
    }
    float* op = comp + ((size_t)b * 64 + og * 16) * HW + hw;
    #pragma unroll
    for (int j = 0; j < 16; j++) op[(size_t)j << lgHW] = acc[j];
}

// ---------------------------------------------------------------------------
// K2: 3x3 conv 64 -> 36, fused pixel-shuffle + softmax over the 9 kernel wts.
// thread = (pixel, pq);  pq uniform per block.  Writes mnorm[b][kk*4+pq][h][w].
// ---------------------------------------------------------------------------
__global__ LB void encoder_k(const float* __restrict__ comp, const float* __restrict__ weT,
                             const float* __restrict__ be, float* __restrict__ mnorm, int lgW)
{
    int lgHW = 2 * lgW;
    int HW = 1 << lgHW, W = 1 << lgW, H = W;
    int idx = blockIdx.x * 256 + threadIdx.x;
    int pq = __builtin_amdgcn_readfirstlane(idx >> (lgHW + 1));
    int pix = idx & (2 * HW - 1);
    int b = pix >> lgHW;
    int hw = pix & (HW - 1);
    int h = hw >> lgW, w = hw & (W - 1);

    int off[9];
    float msk[9];
    #pragma unroll
    for (int ky = 0; ky < 3; ky++) {
        int ys = h + ky - 1;
        bool yok = (unsigned)ys < (unsigned)H;
        #pragma unroll
        for (int kx = 0; kx < 3; kx++) {
            int xs = w + kx - 1;
            bool ok = yok && ((unsigned)xs < (unsigned)W);
            int kt = ky * 3 + kx;
            off[kt] = ok ? ((ys << lgW) + xs) : 0;
            msk[kt] = ok ? 1.f : 0.f;
        }
    }
    float acc[9];
    #pragma unroll
    for (int kk = 0; kk < 9; kk++) acc[kk] = be[kk * 4 + pq];
    const float* wp = weT + pq * 576 * 9;      // [i][kt][kk]
    const float* cb = comp + (size_t)b * 64 * HW;
    for (int i = 0; i < 64; i++) {
        const float* ci = cb + ((size_t)i << lgHW);
        #pragma unroll
        for (int kt = 0; kt < 9; kt++) {
            float cv = ci[off[kt]] * msk[kt];
            const float* wt = wp + (i * 9 + kt) * 9;
            #pragma unroll
            for (int kk = 0; kk < 9; kk++) acc[kk] += wt[kk] * cv;
        }
    }
    // softmax over kk
    float m = acc[0];
    #pragma unroll
    for (int kk = 1; kk < 9; kk++) m = fmaxf(m, acc[kk]);
    float s = 0.f;
    #pragma unroll
    for (int kk = 0; kk < 9; kk++) { acc[kk] = __expf(acc[kk] - m); s += acc[kk]; }
    float r = 1.f / s;
    float* mp = mnorm + (size_t)b * 36 * HW + hw;
    #pragma unroll
    for (int kk = 0; kk < 9; kk++) mp[(size_t)(kk * 4 + pq) << lgHW] = acc[kk] * r;
}

// ---------------------------------------------------------------------------
// K3: content-aware reassembly.  36 per-pixel weights live in VGPRs, reused
// across a 64-channel loop.  out[b][c][2h+p][2w+q] via float2 stores.
// ---------------------------------------------------------------------------
__global__ LB void reassembly_k(const float* __restrict__ x, const float* __restrict__ mnorm,
                                float* __restrict__ out, int lgW)
{
    int lgHW = 2 * lgW;
    int HW = 1 << lgHW, W = 1 << lgW, H = W;
    int lane = threadIdx.x & 63;
    int cg = threadIdx.x >> 6;
    int nbsh = lgHW - 5;                      // pixel-blocks = HW/32 (pow2)
    int pb = blockIdx.x & ((1 << nbsh) - 1);
    int cs = blockIdx.x >> nbsh;              // 0..3 channel split
    int pix = pb * 64 + lane;
    int b = pix >> lgHW;
    int hw = pix & (HW - 1);
    int h = hw >> lgW, w = hw & (W - 1);

    int off[9];
    float msk[9];
    #pragma unroll
    for (int ky = 0; ky < 3; ky++) {
        int ys = h + ky - 1;
        bool yok = (unsigned)ys < (unsigned)H;
        #pragma unroll
        for (int kx = 0; kx < 3; kx++) {
            int xs = w + kx - 1;
            bool ok = yok && ((unsigned)xs < (unsigned)W);
            int kt = ky * 3 + kx;
            off[kt] = ok ? ((ys << lgW) + xs) : 0;
            msk[kt] = ok ? 1.f : 0.f;
        }
    }
    const float* mp = mnorm + (size_t)b * 36 * HW + hw;
    float wreg[36];
    #pragma unroll
    for (int ch = 0; ch < 36; ch++) wreg[ch] = mp[(size_t)ch << lgHW];

    int c0 = (cs * 4 + cg) * 16;
    const float* xb = x + ((size_t)b * 256 + c0) * HW;
    size_t OW = (size_t)W * 2;
    float* ob = out + (((size_t)b * 256 + c0) * 2 * H + 2 * h) * OW + 2 * w;
    for (int it = 0; it < 16; it++) {
        const float* xc = xb + ((size_t)it << lgHW);
        float a00 = 0.f, a01 = 0.f, a10 = 0.f, a11 = 0.f;
        #pragma unroll
        for (int kt = 0; kt < 9; kt++) {
            float tap = xc[off[kt]] * msk[kt];
            a00 += tap * wreg[kt * 4 + 0];
            a01 += tap * wreg[kt * 4 + 1];
            a10 += tap * wreg[kt * 4 + 2];
            a11 += tap * wreg[kt * 4 + 3];
        }
        float* oc = ob + (size_t)it * 2 * H * OW;
        *(float2*)oc = make_float2(a00, a01);
        *(float2*)(oc + OW) = make_float2(a10, a11);
    }
}

// ---------------------------------------------------------------------------
extern "C" void kernel_launch(void* const* d_in, const int* in_sizes, int n_in,
                              void* d_out, int out_size, void* d_ws, size_t ws_size,
                              hipStream_t stream)
{
    const float* src = (const float*)d_in[0];
    const float* wc[4]; const float* bc[4]; const float* we[4]; const float* be[4];
    for (int s = 0; s < 4; s++) {
        wc[s] = (const float*)d_in[2 + 4 * s];
        bc[s] = (const float*)d_in[3 + 4 * s];
        we[s] = (const float*)d_in[4 + 4 * s];
        be[s] = (const float*)d_in[5 + 4 * s];
    }
    float* ws   = (float*)d_ws;
    float* x1   = ws;                    // 2*256*32*32    =   524288
    float* x2   = x1 + 524288;           // 2*256*64*64    =  2097152
    float* x3   = x2 + 2097152;          // 2*256*128*128  =  8388608
    float* comp = x3 + 8388608;          // 2*64*128*128   =  2097152 (max, reused)
    float* mn   = comp + 2097152;        // 2*36*128*128   =  1179648 (max, reused)
    float* wcT  = mn + 1179648;          // 4*16384
    float* weT  = wcT + 65536;           // 4*20736

    prep_weights<<<dim3(81, 8), 256, 0, stream>>>(
        wc[0], wc[1], wc[2], wc[3], we[0], we[1], we[2], we[3], wcT, weT);

    const float* xin = src;
    float* stage_out[4] = {x1, x2, x3, (float*)d_out};
    int lgW = 4;
    for (int s = 0; s < 4; s++) {
        int HW = 1 << (2 * lgW);
        int nb = HW >> 5;                // B*HW/64 blocks
        compress_k<<<nb, 256, 0, stream>>>(xin, wcT + s * 16384, bc[s], comp, lgW);
        encoder_k<<<nb, 256, 0, stream>>>(comp, weT + s * 20736, be[s], mn, lgW);
        reassembly_k<<<nb * 4, 256, 0, stream>>>(xin, mn, stage_out[s], lgW);
        xin = stage_out[s];
        lgW++;
    }
}